// Round 1
// baseline (385.006 us; speedup 1.0000x reference)
//
#include <hip/hip_runtime.h>
#include <hip/hip_bf16.h>

// B=4, T=4096, C=1024, H=64 causal attention w/ RPE bias.
// Pipeline: prep_wT (w -> bf16 w^T) -> proj (x@W via MFMA, writes q,k bf16 + vT bf16)
//        -> flash (online-softmax-free flash attention, fixed m=0; scores bounded).

#define T_DIM 4096
#define C_DIM 1024
#define HD    64
#define QT    32
#define KT    64
#define NQT   128          // T_DIM / QT
#define SCALE 0.125f       // 64^-0.5

typedef __attribute__((ext_vector_type(8))) short s16x8;
typedef __attribute__((ext_vector_type(4))) float f32x4;

__device__ __forceinline__ short f2bf(float f) {
    unsigned u = __builtin_bit_cast(unsigned, f);
    u += 0x7FFFu + ((u >> 16) & 1u);   // round-to-nearest-even
    return (short)(u >> 16);
}

// ---------------------------------------------------------------------------
// Kernel 1: transpose+convert weights: w[c][h] fp32 -> wT[mat][h][c] bf16
// grid: 3 mats x 16 c-tiles = 48 blocks, 256 threads
// ---------------------------------------------------------------------------
__global__ __launch_bounds__(256) void prep_wT(
    const float* __restrict__ wk, const float* __restrict__ wq,
    const float* __restrict__ wv, short* __restrict__ wT)
{
    int mat = blockIdx.x >> 4;
    int c0  = (blockIdx.x & 15) * 64;
    const float* w = (mat == 0) ? wk : ((mat == 1) ? wq : wv);
    __shared__ short lds[64][65];   // [h][c], +1 pad
    #pragma unroll
    for (int rep = 0; rep < 16; ++rep) {
        int idx = threadIdx.x + rep * 256;      // 0..4095
        int c = idx >> 6, h = idx & 63;
        lds[h][c] = f2bf(w[(c0 + c) * 64 + h]); // coalesced read
    }
    __syncthreads();
    #pragma unroll
    for (int rep = 0; rep < 16; ++rep) {
        int idx = threadIdx.x + rep * 256;
        int h = idx >> 6, c = idx & 63;
        wT[mat * (64 * 1024) + h * 1024 + c0 + c] = lds[h][c];  // coalesced write
    }
}

// ---------------------------------------------------------------------------
// Kernel 2: projections. Each block: 32 rows (2 waves x 16), all 3 matrices.
// x A-frags direct global->reg (x read once). wT staged in LDS per 64-slice.
// Outputs: kb, qb natural (B*T, 64) bf16 ; vtb transposed (B, 64, T) bf16.
// grid: 512 blocks x 128 threads
// ---------------------------------------------------------------------------
__global__ __launch_bounds__(128) void proj_kernel(
    const float* __restrict__ x, const short* __restrict__ wT,
    short* __restrict__ kb, short* __restrict__ qb, short* __restrict__ vtb)
{
    __shared__ __align__(16) short wlds[192][72];   // [mat*64+h][c_local], pad->stride 144B
    int w = threadIdx.x >> 6, lane = threadIdx.x & 63;
    int l15 = lane & 15, quad = lane >> 4;
    int m0 = blockIdx.x * 32;

    f32x4 acc[3][4];
    #pragma unroll
    for (int m = 0; m < 3; ++m)
        #pragma unroll
        for (int n = 0; n < 4; ++n) acc[m][n] = (f32x4){0.f, 0.f, 0.f, 0.f};

    const float* xrow = x + (m0 + w * 16 + l15) * C_DIM;

    for (int c0 = 0; c0 < C_DIM; c0 += 64) {
        __syncthreads();
        #pragma unroll
        for (int rep = 0; rep < 12; ++rep) {
            int cid = threadIdx.x + rep * 128;   // 0..1535 : 192 rows x 8 chunks
            int hh = cid >> 3, ch = cid & 7;
            *(s16x8*)&wlds[hh][ch * 8] = *(const s16x8*)&wT[hh * 1024 + c0 + ch * 8];
        }
        __syncthreads();
        #pragma unroll
        for (int ks = 0; ks < 2; ++ks) {
            const float* xp = xrow + c0 + ks * 32 + quad * 8;
            f32x4 x0 = *(const f32x4*)xp;
            f32x4 x1 = *(const f32x4*)(xp + 4);
            s16x8 af;
            af[0] = f2bf(x0[0]); af[1] = f2bf(x0[1]); af[2] = f2bf(x0[2]); af[3] = f2bf(x0[3]);
            af[4] = f2bf(x1[0]); af[5] = f2bf(x1[1]); af[6] = f2bf(x1[2]); af[7] = f2bf(x1[3]);
            #pragma unroll
            for (int mat = 0; mat < 3; ++mat)
                #pragma unroll
                for (int nt = 0; nt < 4; ++nt) {
                    s16x8 bf = *(const s16x8*)&wlds[mat * 64 + nt * 16 + l15][ks * 32 + quad * 8];
                    acc[mat][nt] = __builtin_amdgcn_mfma_f32_16x16x32_bf16(af, bf, acc[mat][nt], 0, 0, 0);
                }
        }
    }
    // C/D layout: col = lane&15 (h within 16-tile), row = quad*4 + r (t within strip)
    #pragma unroll
    for (int nt = 0; nt < 4; ++nt)
        #pragma unroll
        for (int r = 0; r < 4; ++r) {
            int gm = m0 + w * 16 + quad * 4 + r;   // global row in (B*T)
            int h  = nt * 16 + l15;
            kb[gm * 64 + h] = f2bf(acc[0][nt][r]);
            qb[gm * 64 + h] = f2bf(acc[1][nt][r]);
            int b = gm >> 12, t = gm & 4095;
            vtb[((b * 64 + h) << 12) + t] = f2bf(acc[2][nt][r]);
        }
}

// ---------------------------------------------------------------------------
// Kernel 3: flash attention, fixed-m softmax (scores bounded; no online max).
// Block: 128 threads = 2 waves; wave w handles 16 q-rows. QT=32, KT=64.
// grid: 512 blocks (b fastest, qt remapped to pair long+short for balance).
// ---------------------------------------------------------------------------
__global__ __launch_bounds__(128) void flash_kernel(
    const short* __restrict__ qb, const short* __restrict__ kb,
    const short* __restrict__ vtb, const float* __restrict__ bias,
    float* __restrict__ out)
{
    __shared__ __align__(16) short klds[64][72];      // [t_local][h]
    __shared__ __align__(16) short vlds[64][72];      // [h][t_local]  (from vT)
    __shared__ __align__(16) short plds[2][16][72];   // per-wave P staging [row][col]

    int i = blockIdx.x;
    int b = i & 3;
    int j = i >> 2;                                   // 0..127
    int qt = (j & 1) ? (j >> 1) : (NQT - 1 - (j >> 1)); // pair longest+shortest
    int q0 = qt * QT;

    int w = threadIdx.x >> 6, lane = threadIdx.x & 63;
    int l15 = lane & 15, quad = lane >> 4;
    int strip0 = q0 + w * 16;

    // Q A-fragments in registers (2 k-steps over head dim 64)
    const short* qrow = qb + (b * T_DIM + strip0 + l15) * 64;
    s16x8 aq0 = *(const s16x8*)(qrow + quad * 8);
    s16x8 aq1 = *(const s16x8*)(qrow + 32 + quad * 8);

    float l_r[4];
    f32x4 accO[4];
    #pragma unroll
    for (int r = 0; r < 4; ++r) l_r[r] = 0.f;
    #pragma unroll
    for (int nt = 0; nt < 4; ++nt) accO[nt] = (f32x4){0.f, 0.f, 0.f, 0.f};

    int nkt = (q0 + QT - 1) / KT + 1;
    for (int kt = 0; kt < nkt; ++kt) {
        int k0 = kt * KT;
        __syncthreads();
        // stage K tile (natural) + V^T tile: 1024 x 16B chunks / 128 threads
        #pragma unroll
        for (int rep = 0; rep < 8; ++rep) {
            int cid = threadIdx.x + rep * 128;
            int rem = cid & 511, row = rem >> 3, ch = rem & 7;
            if (cid < 512) {
                *(s16x8*)&klds[row][ch * 8] =
                    *(const s16x8*)&kb[(b * T_DIM + k0 + row) * 64 + ch * 8];
            } else {
                *(s16x8*)&vlds[row][ch * 8] =
                    *(const s16x8*)&vtb[(b * 64 + row) * T_DIM + k0 + ch * 8];
            }
        }
        __syncthreads();

        // bias loads (independent of MFMA; overlap with QK)
        float s[4][4];
        #pragma unroll
        for (int nt = 0; nt < 4; ++nt)
            #pragma unroll
            for (int r = 0; r < 4; ++r)
                s[nt][r] = bias[(strip0 + quad * 4 + r) * T_DIM + k0 + nt * 16 + l15];

        // S = Q K^T  (B-frag: row n of K natural = B^T rows)
        f32x4 accS[4];
        #pragma unroll
        for (int nt = 0; nt < 4; ++nt) accS[nt] = (f32x4){0.f, 0.f, 0.f, 0.f};
        #pragma unroll
        for (int nt = 0; nt < 4; ++nt) {
            s16x8 b0 = *(const s16x8*)&klds[nt * 16 + l15][quad * 8];
            accS[nt] = __builtin_amdgcn_mfma_f32_16x16x32_bf16(aq0, b0, accS[nt], 0, 0, 0);
            s16x8 b1 = *(const s16x8*)&klds[nt * 16 + l15][32 + quad * 8];
            accS[nt] = __builtin_amdgcn_mfma_f32_16x16x32_bf16(aq1, b1, accS[nt], 0, 0, 0);
        }

        // scores = S*scale + bias ; causal mask; p = exp(s) (fixed m=0, bounded)
        #pragma unroll
        for (int nt = 0; nt < 4; ++nt)
            #pragma unroll
            for (int r = 0; r < 4; ++r)
                s[nt][r] = accS[nt][r] * SCALE + s[nt][r];

        if (k0 + KT - 1 > strip0) {   // tile touches/crosses the diagonal
            #pragma unroll
            for (int nt = 0; nt < 4; ++nt)
                #pragma unroll
                for (int r = 0; r < 4; ++r)
                    if (k0 + nt * 16 + l15 > strip0 + quad * 4 + r)
                        s[nt][r] = -__builtin_inff();
        }
        #pragma unroll
        for (int nt = 0; nt < 4; ++nt)
            #pragma unroll
            for (int r = 0; r < 4; ++r) {
                float p = __expf(s[nt][r]);
                s[nt][r] = p;
                l_r[r] += p;          // per-lane partial row sum; reduced once at end
            }

        // P -> LDS (C/D layout scatter), then read back as A-fragments
        #pragma unroll
        for (int nt = 0; nt < 4; ++nt)
            #pragma unroll
            for (int r = 0; r < 4; ++r)
                plds[w][quad * 4 + r][nt * 16 + l15] = f2bf(s[nt][r]);

        s16x8 ap0 = *(const s16x8*)&plds[w][l15][quad * 8];
        s16x8 ap1 = *(const s16x8*)&plds[w][l15][32 + quad * 8];
        #pragma unroll
        for (int nt = 0; nt < 4; ++nt) {
            s16x8 bv0 = *(const s16x8*)&vlds[nt * 16 + l15][quad * 8];
            accO[nt] = __builtin_amdgcn_mfma_f32_16x16x32_bf16(ap0, bv0, accO[nt], 0, 0, 0);
            s16x8 bv1 = *(const s16x8*)&vlds[nt * 16 + l15][32 + quad * 8];
            accO[nt] = __builtin_amdgcn_mfma_f32_16x16x32_bf16(ap1, bv1, accO[nt], 0, 0, 0);
        }
    }

    // final row-sum reduction (once), normalize, store fp32
    float inv[4];
    #pragma unroll
    for (int r = 0; r < 4; ++r) {
        float rs = l_r[r];
        #pragma unroll
        for (int d = 1; d < 16; d <<= 1) rs += __shfl_xor(rs, d, 64);
        inv[r] = 1.0f / rs;
    }
    #pragma unroll
    for (int nt = 0; nt < 4; ++nt)
        #pragma unroll
        for (int r = 0; r < 4; ++r)
            out[(b * T_DIM + strip0 + quad * 4 + r) * 64 + nt * 16 + l15] =
                accO[nt][r] * inv[r];
}

// ---------------------------------------------------------------------------
extern "C" void kernel_launch(void* const* d_in, const int* in_sizes, int n_in,
                              void* d_out, int out_size, void* d_ws, size_t ws_size,
                              hipStream_t stream) {
    (void)in_sizes; (void)n_in; (void)out_size; (void)ws_size;
    const float* x    = (const float*)d_in[0];
    const float* bias = (const float*)d_in[1];
    const float* wk   = (const float*)d_in[2];
    const float* wq   = (const float*)d_in[3];
    const float* wv   = (const float*)d_in[4];
    float* out = (float*)d_out;

    short* wT  = (short*)d_ws;              // 3*64*1024
    short* kb  = wT + 3 * 64 * 1024;        // 16384*64
    short* qb  = kb + 16384 * 64;
    short* vtb = qb + 16384 * 64;           // (B,64,T)

    prep_wT<<<dim3(48), dim3(256), 0, stream>>>(wk, wq, wv, wT);
    proj_kernel<<<dim3(512), dim3(128), 0, stream>>>(x, wT, kb, qb, vtb);
    flash_kernel<<<dim3(512), dim3(128), 0, stream>>>(qb, kb, vtb, bias, out);
}

// Round 2
// 224.102 us; speedup vs baseline: 1.7180x; 1.7180x over previous
//
#include <hip/hip_runtime.h>
#include <hip/hip_bf16.h>

// B=4, T=4096, C=1024, H=64 causal attention w/ RPE bias.
// Round 2: occupancy fix. Both proj and flash were pinned at 4 waves/CU
// (16 rows/wave is fixed by MFMA M=16). Split the reduction dims:
//   proj: C split in 2 halves (8 waves/CU), fp32 partials + combine kernel.
//   flash: key range split in 1024-chunks (10 waves/CU). Fixed-m=0 softmax
//          makes partials trivially additive (no max rescale): O_p, l_p sums.

#define T_DIM 4096
#define C_DIM 1024
#define QT    32
#define KT    64
#define CK    1024         // flash key-chunk
#define SCALE 0.125f       // 64^-0.5

typedef __attribute__((ext_vector_type(8))) short s16x8;
typedef __attribute__((ext_vector_type(4))) float f32x4;

__device__ __forceinline__ short f2bf(float f) {
    unsigned u = __builtin_bit_cast(unsigned, f);
    u += 0x7FFFu + ((u >> 16) & 1u);   // round-to-nearest-even
    return (short)(u >> 16);
}

// ---------------------------------------------------------------------------
// Kernel 1: transpose+convert weights: w[c][h] fp32 -> wT[mat][h][c] bf16
// ---------------------------------------------------------------------------
__global__ __launch_bounds__(256) void prep_wT(
    const float* __restrict__ wk, const float* __restrict__ wq,
    const float* __restrict__ wv, short* __restrict__ wT)
{
    int mat = blockIdx.x >> 4;
    int c0  = (blockIdx.x & 15) * 64;
    const float* w = (mat == 0) ? wk : ((mat == 1) ? wq : wv);
    __shared__ short lds[64][65];
    #pragma unroll
    for (int rep = 0; rep < 16; ++rep) {
        int idx = threadIdx.x + rep * 256;
        int c = idx >> 6, h = idx & 63;
        lds[h][c] = f2bf(w[(c0 + c) * 64 + h]);
    }
    __syncthreads();
    #pragma unroll
    for (int rep = 0; rep < 16; ++rep) {
        int idx = threadIdx.x + rep * 256;
        int h = idx >> 6, c = idx & 63;
        wT[mat * (64 * 1024) + h * 1024 + c0 + c] = lds[h][c];
    }
}

// ---------------------------------------------------------------------------
// Kernel 2: projection partials. Block: 32 rows x 512-of-C, all 3 matrices.
// grid (512, 2) x 128 thr -> 1024 blocks = 2048 waves = 8 waves/CU.
// pp[half][row][mat*64+h] fp32.
// ---------------------------------------------------------------------------
__global__ __launch_bounds__(128) void proj_part(
    const float* __restrict__ x, const short* __restrict__ wT,
    float* __restrict__ pp)
{
    __shared__ __align__(16) short wlds[192][72];
    int w = threadIdx.x >> 6, lane = threadIdx.x & 63;
    int l15 = lane & 15, quad = lane >> 4;
    int m0 = blockIdx.x * 32;
    int cbase = blockIdx.y * 512;

    f32x4 acc[3][4];
    #pragma unroll
    for (int m = 0; m < 3; ++m)
        #pragma unroll
        for (int n = 0; n < 4; ++n) acc[m][n] = (f32x4){0.f, 0.f, 0.f, 0.f};

    const float* xrow = x + (size_t)(m0 + w * 16 + l15) * C_DIM;

    for (int s = 0; s < 8; ++s) {
        int c0 = cbase + s * 64;
        // prefetch x (global, independent of LDS) before the barrier
        f32x4 x0 = *(const f32x4*)(xrow + c0 + quad * 8);
        f32x4 x1 = *(const f32x4*)(xrow + c0 + quad * 8 + 4);
        f32x4 x2 = *(const f32x4*)(xrow + c0 + 32 + quad * 8);
        f32x4 x3 = *(const f32x4*)(xrow + c0 + 32 + quad * 8 + 4);
        __syncthreads();   // prev slice fully consumed
        #pragma unroll
        for (int rep = 0; rep < 12; ++rep) {
            int cid = threadIdx.x + rep * 128;   // 192 rows x 8 chunks
            int hh = cid >> 3, ch = cid & 7;
            *(s16x8*)&wlds[hh][ch * 8] = *(const s16x8*)&wT[hh * 1024 + c0 + ch * 8];
        }
        __syncthreads();
        s16x8 af[2];
        af[0][0] = f2bf(x0[0]); af[0][1] = f2bf(x0[1]); af[0][2] = f2bf(x0[2]); af[0][3] = f2bf(x0[3]);
        af[0][4] = f2bf(x1[0]); af[0][5] = f2bf(x1[1]); af[0][6] = f2bf(x1[2]); af[0][7] = f2bf(x1[3]);
        af[1][0] = f2bf(x2[0]); af[1][1] = f2bf(x2[1]); af[1][2] = f2bf(x2[2]); af[1][3] = f2bf(x2[3]);
        af[1][4] = f2bf(x3[0]); af[1][5] = f2bf(x3[1]); af[1][6] = f2bf(x3[2]); af[1][7] = f2bf(x3[3]);
        #pragma unroll
        for (int ks = 0; ks < 2; ++ks)
            #pragma unroll
            for (int mat = 0; mat < 3; ++mat)
                #pragma unroll
                for (int nt = 0; nt < 4; ++nt) {
                    s16x8 bf = *(const s16x8*)&wlds[mat * 64 + nt * 16 + l15][ks * 32 + quad * 8];
                    acc[mat][nt] = __builtin_amdgcn_mfma_f32_16x16x32_bf16(af[ks], bf, acc[mat][nt], 0, 0, 0);
                }
    }
    #pragma unroll
    for (int nt = 0; nt < 4; ++nt)
        #pragma unroll
        for (int r = 0; r < 4; ++r) {
            int gm = m0 + w * 16 + quad * 4 + r;
            float* prow = pp + ((size_t)blockIdx.y * 16384 + gm) * 192;
            prow[0 * 64 + nt * 16 + l15] = acc[0][nt][r];
            prow[1 * 64 + nt * 16 + l15] = acc[1][nt][r];
            prow[2 * 64 + nt * 16 + l15] = acc[2][nt][r];
        }
}

// ---------------------------------------------------------------------------
// Kernel 3: combine halves -> bf16 kb, qb + transposed vtb (B,64,T).
// grid 256 x 256: each block 64 rows.
// ---------------------------------------------------------------------------
__global__ __launch_bounds__(256) void proj_combine(
    const float* __restrict__ pp, short* __restrict__ kb,
    short* __restrict__ qb, short* __restrict__ vtb)
{
    int m0 = blockIdx.x * 64;
    __shared__ short vt[64][72];
    #pragma unroll
    for (int rep = 0; rep < 48; ++rep) {
        int idx = rep * 256 + threadIdx.x;       // 64 rows x 192 cols
        int row = idx / 192, col = idx - row * 192;
        size_t o = (size_t)(m0 + row) * 192 + col;
        float sum = pp[o] + pp[(size_t)16384 * 192 + o];
        short v = f2bf(sum);
        if (col < 64)       kb[(m0 + row) * 64 + col] = v;
        else if (col < 128) qb[(m0 + row) * 64 + (col - 64)] = v;
        else                vt[col - 128][row] = v;
    }
    __syncthreads();
    int b = m0 >> 12, t0 = m0 & 4095;            // 64-row tile within one b
    #pragma unroll
    for (int rep = 0; rep < 16; ++rep) {
        int idx = rep * 256 + threadIdx.x;       // 64 h x 64 t
        int h = idx >> 6, tl = idx & 63;
        vtb[((b * 64 + h) << 12) + t0 + tl] = vt[h][tl];
    }
}

// ---------------------------------------------------------------------------
// Kernel 4: flash partials. grid (4, 128, 4): b, q-tile(32), key-chunk(1024).
// Fixed m=0 softmax -> partials additive. po[b][qt][c]: 32x64 O + 32 l fp32.
// ---------------------------------------------------------------------------
__global__ __launch_bounds__(128) void flash_part(
    const short* __restrict__ qb, const short* __restrict__ kb,
    const short* __restrict__ vtb, const float* __restrict__ bias,
    float* __restrict__ po)
{
    int b = blockIdx.x, qt = blockIdx.y, c = blockIdx.z;
    int q0 = qt * QT;
    int kstart = c * CK;
    int kend = min(kstart + CK, q0 + QT);
    if (kstart >= kend) return;                  // uniform early exit

    __shared__ __align__(16) short klds[64][72];
    __shared__ __align__(16) short vlds[64][72];
    __shared__ __align__(16) short plds[2][16][72];

    int w = threadIdx.x >> 6, lane = threadIdx.x & 63;
    int l15 = lane & 15, quad = lane >> 4;
    int strip0 = q0 + w * 16;

    const short* qrow = qb + (size_t)(b * T_DIM + strip0 + l15) * 64;
    s16x8 aq0 = *(const s16x8*)(qrow + quad * 8);
    s16x8 aq1 = *(const s16x8*)(qrow + 32 + quad * 8);

    float l_r[4];
    f32x4 accO[4];
    #pragma unroll
    for (int r = 0; r < 4; ++r) l_r[r] = 0.f;
    #pragma unroll
    for (int nt = 0; nt < 4; ++nt) accO[nt] = (f32x4){0.f, 0.f, 0.f, 0.f};

    for (int k0 = kstart; k0 < kend; k0 += KT) {
        // bias loads issued BEFORE the barrier (global only; overlap the wait)
        float s[4][4];
        #pragma unroll
        for (int nt = 0; nt < 4; ++nt)
            #pragma unroll
            for (int r = 0; r < 4; ++r)
                s[nt][r] = bias[(size_t)(strip0 + quad * 4 + r) * T_DIM + k0 + nt * 16 + l15];

        __syncthreads();
        #pragma unroll
        for (int rep = 0; rep < 8; ++rep) {
            int cid = threadIdx.x + rep * 128;
            int rem = cid & 511, row = rem >> 3, ch = rem & 7;
            if (cid < 512) {
                *(s16x8*)&klds[row][ch * 8] =
                    *(const s16x8*)&kb[(size_t)(b * T_DIM + k0 + row) * 64 + ch * 8];
            } else {
                *(s16x8*)&vlds[row][ch * 8] =
                    *(const s16x8*)&vtb[((size_t)(b * 64 + row) << 12) + k0 + ch * 8];
            }
        }
        __syncthreads();

        f32x4 accS[4];
        #pragma unroll
        for (int nt = 0; nt < 4; ++nt) accS[nt] = (f32x4){0.f, 0.f, 0.f, 0.f};
        #pragma unroll
        for (int nt = 0; nt < 4; ++nt) {
            s16x8 b0 = *(const s16x8*)&klds[nt * 16 + l15][quad * 8];
            accS[nt] = __builtin_amdgcn_mfma_f32_16x16x32_bf16(aq0, b0, accS[nt], 0, 0, 0);
            s16x8 b1 = *(const s16x8*)&klds[nt * 16 + l15][32 + quad * 8];
            accS[nt] = __builtin_amdgcn_mfma_f32_16x16x32_bf16(aq1, b1, accS[nt], 0, 0, 0);
        }

        #pragma unroll
        for (int nt = 0; nt < 4; ++nt)
            #pragma unroll
            for (int r = 0; r < 4; ++r)
                s[nt][r] = accS[nt][r] * SCALE + s[nt][r];

        if (k0 + KT - 1 > strip0) {   // tile touches/crosses diagonal
            #pragma unroll
            for (int nt = 0; nt < 4; ++nt)
                #pragma unroll
                for (int r = 0; r < 4; ++r)
                    if (k0 + nt * 16 + l15 > strip0 + quad * 4 + r)
                        s[nt][r] = -__builtin_inff();
        }
        #pragma unroll
        for (int nt = 0; nt < 4; ++nt)
            #pragma unroll
            for (int r = 0; r < 4; ++r) {
                float p = __expf(s[nt][r]);
                s[nt][r] = p;
                l_r[r] += p;
            }

        #pragma unroll
        for (int nt = 0; nt < 4; ++nt)
            #pragma unroll
            for (int r = 0; r < 4; ++r)
                plds[w][quad * 4 + r][nt * 16 + l15] = f2bf(s[nt][r]);

        s16x8 ap0 = *(const s16x8*)&plds[w][l15][quad * 8];
        s16x8 ap1 = *(const s16x8*)&plds[w][l15][32 + quad * 8];
        #pragma unroll
        for (int nt = 0; nt < 4; ++nt) {
            s16x8 bv0 = *(const s16x8*)&vlds[nt * 16 + l15][quad * 8];
            accO[nt] = __builtin_amdgcn_mfma_f32_16x16x32_bf16(ap0, bv0, accO[nt], 0, 0, 0);
            s16x8 bv1 = *(const s16x8*)&vlds[nt * 16 + l15][32 + quad * 8];
            accO[nt] = __builtin_amdgcn_mfma_f32_16x16x32_bf16(ap1, bv1, accO[nt], 0, 0, 0);
        }
    }

    // partial store: O rows (local), then l per row (butterfly over 16 lanes)
    float* base = po + (size_t)(((b * 128 + qt) * 4) + c) * 2080;
    #pragma unroll
    for (int nt = 0; nt < 4; ++nt)
        #pragma unroll
        for (int r = 0; r < 4; ++r)
            base[(w * 16 + quad * 4 + r) * 64 + nt * 16 + l15] = accO[nt][r];
    #pragma unroll
    for (int r = 0; r < 4; ++r) {
        float rs = l_r[r];
        #pragma unroll
        for (int d = 1; d < 16; d <<= 1) rs += __shfl_xor(rs, d, 64);
        if (l15 == 0) base[2048 + w * 16 + quad * 4 + r] = rs;
    }
}

// ---------------------------------------------------------------------------
// Kernel 5: reduce flash partials + normalize. 1024 x 256, f32x4 per thread.
// ---------------------------------------------------------------------------
__global__ __launch_bounds__(256) void flash_reduce(
    const float* __restrict__ po, float* __restrict__ out)
{
    int idx = blockIdx.x * 256 + threadIdx.x;    // 262144 chunks of 4 floats
    int row = idx >> 4, c4 = idx & 15;           // row in (B*T)
    int b = row >> 12, t = row & 4095;
    int qt = t >> 5, rloc = t & 31;
    int nc = (t >> 10) + 1;                      // chunks covering [0, t]
    f32x4 o = (f32x4){0.f, 0.f, 0.f, 0.f};
    float l = 0.f;
    for (int c = 0; c < nc; ++c) {
        const float* base = po + (size_t)(((b * 128 + qt) * 4) + c) * 2080;
        f32x4 v = *(const f32x4*)&base[rloc * 64 + c4 * 4];
        o[0] += v[0]; o[1] += v[1]; o[2] += v[2]; o[3] += v[3];
        l += base[2048 + rloc];
    }
    float inv = 1.0f / l;
    f32x4 res = (f32x4){o[0] * inv, o[1] * inv, o[2] * inv, o[3] * inv};
    *(f32x4*)&out[(size_t)row * 64 + c4 * 4] = res;
}

// ---------------------------------------------------------------------------
extern "C" void kernel_launch(void* const* d_in, const int* in_sizes, int n_in,
                              void* d_out, int out_size, void* d_ws, size_t ws_size,
                              hipStream_t stream) {
    (void)in_sizes; (void)n_in; (void)out_size; (void)ws_size;
    const float* x    = (const float*)d_in[0];
    const float* bias = (const float*)d_in[1];
    const float* wk   = (const float*)d_in[2];
    const float* wq   = (const float*)d_in[3];
    const float* wv   = (const float*)d_in[4];
    float* out = (float*)d_out;

    short* wT  = (short*)d_ws;              // 3*64*1024 shorts
    short* kb  = wT + 3 * 64 * 1024;        // 16384*64 shorts each
    short* qb  = kb + 16384 * 64;
    short* vtb = qb + 16384 * 64;
    float* pp  = (float*)(vtb + 16384 * 64);          // 2*16384*192 fp32 (25.2 MB)
    float* po  = pp + (size_t)2 * 16384 * 192;        // 4*128*4*2080 fp32 (17.0 MB)

    prep_wT<<<dim3(48), dim3(256), 0, stream>>>(wk, wq, wv, wT);
    proj_part<<<dim3(512, 2), dim3(128), 0, stream>>>(x, wT, pp);
    proj_combine<<<dim3(256), dim3(256), 0, stream>>>(pp, kb, qb, vtb);
    flash_part<<<dim3(4, 128, 4), dim3(128), 0, stream>>>(qb, kb, vtb, bias, po);
    flash_reduce<<<dim3(1024), dim3(256), 0, stream>>>(po, out);
}

// Round 3
// 221.766 us; speedup vs baseline: 1.7361x; 1.0105x over previous
//
#include <hip/hip_runtime.h>
#include <hip/hip_bf16.h>

// B=4, T=4096, C=1024, H=64 causal attention w/ RPE bias.
// Round 3: (a) flash computes S^T = K Q^T so bias loads are dwordx4 and the
// P->LDS round-trip is ds_write_b64 (was 16 scalar each); 4-wave blocks,
// CK=512 (18 waves/CU). (b) proj is a barrier-free streaming GEMM: weights
// pre-laid-out in B-fragment order, loaded dwordx4 from L2; split-C=4 with
// bf16 partials. SCALE folded into w_q at prep.

#define T_DIM 4096
#define C_DIM 1024
#define QT    64
#define KT    64
#define CK    512

typedef __attribute__((ext_vector_type(8))) short s16x8;
typedef __attribute__((ext_vector_type(4))) float f32x4;
typedef __attribute__((ext_vector_type(2))) unsigned int u32x2;

__device__ __forceinline__ short f2bf(float f) {
    unsigned u = __builtin_bit_cast(unsigned, f);
    u += 0x7FFFu + ((u >> 16) & 1u);
    return (short)(u >> 16);
}
__device__ __forceinline__ unsigned pack2(float a, float b) {
    unsigned ua = __builtin_bit_cast(unsigned, a);
    unsigned ub = __builtin_bit_cast(unsigned, b);
    ua += 0x7FFFu + ((ua >> 16) & 1u);
    ub += 0x7FFFu + ((ub >> 16) & 1u);
    return __builtin_amdgcn_perm(ub, ua, 0x07060302u);
}
__device__ __forceinline__ float bf2f(short s) {
    unsigned u = ((unsigned)(unsigned short)s) << 16;
    return __builtin_bit_cast(float, u);
}

// ---------------------------------------------------------------------------
// Kernel 1: weights -> B-fragment order: wfrag[ksAll][mat][nt][lane][8] bf16.
// w_q scaled by 0.125. grid (32, 3) x 256.
// ---------------------------------------------------------------------------
__global__ __launch_bounds__(256) void prep_frag(
    const float* __restrict__ wk, const float* __restrict__ wq,
    const float* __restrict__ wv, short* __restrict__ wfrag)
{
    int ksAll = blockIdx.x, mat = blockIdx.y;
    const float* w = (mat == 0) ? wk : ((mat == 1) ? wq : wv);
    float sc = (mat == 1) ? 0.125f : 1.0f;
    int nt = threadIdx.x >> 6, lane = threadIdx.x & 63;
    int quad = lane >> 4, l15 = lane & 15;
    int h = nt * 16 + l15;
    int cb = ksAll * 32 + quad * 8;
    s16x8 v;
    #pragma unroll
    for (int j = 0; j < 8; ++j) v[j] = f2bf(w[(cb + j) * 64 + h] * sc);
    *(s16x8*)&wfrag[((ksAll * 12 + mat * 4 + nt) * 64 + lane) * 8] = v;
}

// ---------------------------------------------------------------------------
// Kernel 2: streaming projection partials, no LDS / no barriers.
// grid (256, 4) x 256 thr = 4096 waves = 16/CU. pp[cq][row][mat*64+h] bf16.
// ---------------------------------------------------------------------------
__global__ __launch_bounds__(256, 2) void proj_part(
    const float* __restrict__ x, const short* __restrict__ wfrag,
    short* __restrict__ pp)
{
    int w = threadIdx.x >> 6, lane = threadIdx.x & 63;
    int l15 = lane & 15, quad = lane >> 4;
    int row0 = (blockIdx.x * 4 + w) * 16;
    int cq = blockIdx.y;

    f32x4 acc[12];
    #pragma unroll
    for (int i = 0; i < 12; ++i) acc[i] = (f32x4){0.f, 0.f, 0.f, 0.f};

    const float* xrow = x + (size_t)(row0 + l15) * C_DIM + cq * 256;

    #pragma unroll
    for (int ks = 0; ks < 8; ++ks) {
        int ksAll = cq * 8 + ks;
        const s16x8* fb = (const s16x8*)&wfrag[(size_t)(ksAll * 12 * 64 + lane) * 8];
        f32x4 x0 = *(const f32x4*)(xrow + ks * 32 + quad * 8);
        f32x4 x1 = *(const f32x4*)(xrow + ks * 32 + quad * 8 + 4);
        s16x8 af;
        unsigned p0 = pack2(x0[0], x0[1]), p1 = pack2(x0[2], x0[3]);
        unsigned p2 = pack2(x1[0], x1[1]), p3 = pack2(x1[2], x1[3]);
        af[0] = (short)p0; af[1] = (short)(p0 >> 16);
        af[2] = (short)p1; af[3] = (short)(p1 >> 16);
        af[4] = (short)p2; af[5] = (short)(p2 >> 16);
        af[6] = (short)p3; af[7] = (short)(p3 >> 16);
        #pragma unroll
        for (int f = 0; f < 12; ++f) {
            s16x8 bf = fb[f * 64];
            acc[f] = __builtin_amdgcn_mfma_f32_16x16x32_bf16(af, bf, acc[f], 0, 0, 0);
        }
    }
    short* base = pp + (size_t)cq * 16384 * 192;
    #pragma unroll
    for (int f = 0; f < 12; ++f) {
        int mat = f >> 2, nt = f & 3;
        #pragma unroll
        for (int r = 0; r < 4; ++r)
            base[(size_t)(row0 + quad * 4 + r) * 192 + mat * 64 + nt * 16 + l15] =
                f2bf(acc[f][r]);
    }
}

// ---------------------------------------------------------------------------
// Kernel 3: combine 4 partials -> kb, qb bf16 + transposed vtb (B,64,T).
// ---------------------------------------------------------------------------
__global__ __launch_bounds__(256) void proj_combine(
    const short* __restrict__ pp, short* __restrict__ kb,
    short* __restrict__ qb, short* __restrict__ vtb)
{
    int m0 = blockIdx.x * 64;
    __shared__ short vt[64][72];
    #pragma unroll
    for (int o = 0; o < 6; ++o) {
        int oct = o * 256 + threadIdx.x;          // 64 rows x 24 octets
        int row = oct / 24, c8 = (oct - row * 24) * 8;
        float s[8];
        #pragma unroll
        for (int j = 0; j < 8; ++j) s[j] = 0.f;
        #pragma unroll
        for (int cq = 0; cq < 4; ++cq) {
            s16x8 v = *(const s16x8*)&pp[((size_t)cq * 16384 + m0 + row) * 192 + c8];
            #pragma unroll
            for (int j = 0; j < 8; ++j) s[j] += bf2f(v[j]);
        }
        s16x8 r;
        #pragma unroll
        for (int j = 0; j < 4; ++j) {
            unsigned d = pack2(s[2 * j], s[2 * j + 1]);
            r[2 * j] = (short)d; r[2 * j + 1] = (short)(d >> 16);
        }
        if (c8 < 64)        *(s16x8*)&kb[(size_t)(m0 + row) * 64 + c8] = r;
        else if (c8 < 128)  *(s16x8*)&qb[(size_t)(m0 + row) * 64 + (c8 - 64)] = r;
        else {
            #pragma unroll
            for (int j = 0; j < 8; ++j) vt[c8 - 128 + j][row] = r[j];
        }
    }
    __syncthreads();
    int b = m0 >> 12, t0 = m0 & 4095;
    #pragma unroll
    for (int o = 0; o < 2; ++o) {
        int oct = o * 256 + threadIdx.x;          // 64 h x 8 octets
        int h = oct >> 3, tl = (oct & 7) * 8;
        s16x8 v = *(const s16x8*)&vt[h][tl];
        *(s16x8*)&vtb[(((size_t)b * 64 + h) << 12) + t0 + tl] = v;
    }
}

// ---------------------------------------------------------------------------
// Kernel 4: flash partials, S^T form, fixed m=0 softmax.
// grid (64 qt, 8 chunk, 4 b) x 256 thr. po row: 64x64 O + 64 l, bf16.
// ---------------------------------------------------------------------------
__global__ __launch_bounds__(256) void flash_part(
    const short* __restrict__ qb, const short* __restrict__ kb,
    const short* __restrict__ vtb, const float* __restrict__ bias,
    short* __restrict__ po)
{
    int qt = blockIdx.x, c = blockIdx.y, b = blockIdx.z;
    int q0 = qt * QT;
    int kstart = c * CK;
    int kend = min(kstart + CK, q0 + QT);
    if (kstart >= kend) return;                   // block-uniform

    __shared__ __align__(16) short klds[64][72];
    __shared__ __align__(16) short vlds[64][72];
    __shared__ __align__(16) short plds[4][16][72];

    int w = threadIdx.x >> 6, lane = threadIdx.x & 63;
    int l15 = lane & 15, quad = lane >> 4;
    int strip0 = q0 + w * 16;

    const short* qrow = qb + (size_t)(b * T_DIM + strip0 + l15) * 64;
    s16x8 aq0 = *(const s16x8*)(qrow + quad * 8);
    s16x8 aq1 = *(const s16x8*)(qrow + 32 + quad * 8);

    float l_sum = 0.f;
    f32x4 accO[4];
    #pragma unroll
    for (int nt = 0; nt < 4; ++nt) accO[nt] = (f32x4){0.f, 0.f, 0.f, 0.f};

    const float* brow = bias + (size_t)(strip0 + l15) * T_DIM;

    for (int k0 = kstart; k0 < kend; k0 += KT) {
        f32x4 vb[4];
        #pragma unroll
        for (int nt = 0; nt < 4; ++nt)
            vb[nt] = *(const f32x4*)&brow[k0 + nt * 16 + quad * 4];

        __syncthreads();
        #pragma unroll
        for (int rep = 0; rep < 4; ++rep) {
            int cid = threadIdx.x + rep * 256;
            int rem = cid & 511, row = rem >> 3, ch = rem & 7;
            if (cid < 512)
                *(s16x8*)&klds[row][ch * 8] =
                    *(const s16x8*)&kb[(size_t)(b * T_DIM + k0 + row) * 64 + ch * 8];
            else
                *(s16x8*)&vlds[row][ch * 8] =
                    *(const s16x8*)&vtb[(((size_t)b * 64 + row) << 12) + k0 + ch * 8];
        }
        __syncthreads();

        // S^T = K Q^T
        f32x4 accS[4];
        #pragma unroll
        for (int nt = 0; nt < 4; ++nt) accS[nt] = (f32x4){0.f, 0.f, 0.f, 0.f};
        #pragma unroll
        for (int nt = 0; nt < 4; ++nt) {
            s16x8 a0 = *(const s16x8*)&klds[nt * 16 + l15][quad * 8];
            accS[nt] = __builtin_amdgcn_mfma_f32_16x16x32_bf16(a0, aq0, accS[nt], 0, 0, 0);
            s16x8 a1 = *(const s16x8*)&klds[nt * 16 + l15][32 + quad * 8];
            accS[nt] = __builtin_amdgcn_mfma_f32_16x16x32_bf16(a1, aq1, accS[nt], 0, 0, 0);
        }

        int qrow_g = strip0 + l15;
        bool diag = (k0 + KT - 1 > strip0);
        #pragma unroll
        for (int nt = 0; nt < 4; ++nt) {
            float sv[4];
            #pragma unroll
            for (int r = 0; r < 4; ++r) {
                sv[r] = accS[nt][r] + vb[nt][r];
                if (diag && (k0 + nt * 16 + quad * 4 + r > qrow_g))
                    sv[r] = -__builtin_inff();
                float p = __expf(sv[r]);
                sv[r] = p;
                l_sum += p;
            }
            u32x2 d;
            d[0] = pack2(sv[0], sv[1]);
            d[1] = pack2(sv[2], sv[3]);
            *(u32x2*)&plds[w][l15][nt * 16 + quad * 4] = d;
        }

        s16x8 ap0 = *(const s16x8*)&plds[w][l15][quad * 8];
        s16x8 ap1 = *(const s16x8*)&plds[w][l15][32 + quad * 8];
        #pragma unroll
        for (int nt = 0; nt < 4; ++nt) {
            s16x8 bv0 = *(const s16x8*)&vlds[nt * 16 + l15][quad * 8];
            accO[nt] = __builtin_amdgcn_mfma_f32_16x16x32_bf16(ap0, bv0, accO[nt], 0, 0, 0);
            s16x8 bv1 = *(const s16x8*)&vlds[nt * 16 + l15][32 + quad * 8];
            accO[nt] = __builtin_amdgcn_mfma_f32_16x16x32_bf16(ap1, bv1, accO[nt], 0, 0, 0);
        }
    }

    l_sum += __shfl_xor(l_sum, 16, 64);
    l_sum += __shfl_xor(l_sum, 32, 64);

    short* base = po + (size_t)(((b * 64 + qt) * 8) + c) * 4160;
    #pragma unroll
    for (int nt = 0; nt < 4; ++nt)
        #pragma unroll
        for (int r = 0; r < 4; ++r)
            base[(w * 16 + quad * 4 + r) * 64 + nt * 16 + l15] = f2bf(accO[nt][r]);
    if (quad == 0) base[4096 + w * 16 + l15] = f2bf(l_sum);
}

// ---------------------------------------------------------------------------
// Kernel 5: reduce partials + normalize. 1024 x 256.
// ---------------------------------------------------------------------------
__global__ __launch_bounds__(256) void flash_reduce(
    const short* __restrict__ po, float* __restrict__ out)
{
    int idx = blockIdx.x * 256 + threadIdx.x;
    int row = idx >> 4, c4 = idx & 15;
    int b = row >> 12, t = row & 4095;
    int qt = t >> 6, rloc = t & 63;
    int nc = (t >> 9) + 1;
    float o0 = 0.f, o1 = 0.f, o2 = 0.f, o3 = 0.f, l = 0.f;
    for (int cc = 0; cc < nc; ++cc) {
        const short* base = po + (size_t)(((b * 64 + qt) * 8) + cc) * 4160;
        const short* p = &base[rloc * 64 + c4 * 4];
        o0 += bf2f(p[0]); o1 += bf2f(p[1]); o2 += bf2f(p[2]); o3 += bf2f(p[3]);
        l += bf2f(base[4096 + rloc]);
    }
    float inv = 1.0f / l;
    f32x4 res = (f32x4){o0 * inv, o1 * inv, o2 * inv, o3 * inv};
    *(f32x4*)&out[(size_t)row * 64 + c4 * 4] = res;
}

// ---------------------------------------------------------------------------
extern "C" void kernel_launch(void* const* d_in, const int* in_sizes, int n_in,
                              void* d_out, int out_size, void* d_ws, size_t ws_size,
                              hipStream_t stream) {
    (void)in_sizes; (void)n_in; (void)out_size; (void)ws_size;
    const float* x    = (const float*)d_in[0];
    const float* bias = (const float*)d_in[1];
    const float* wk   = (const float*)d_in[2];
    const float* wq   = (const float*)d_in[3];
    const float* wv   = (const float*)d_in[4];
    float* out = (float*)d_out;

    short* wfrag = (short*)d_ws;                       // 196608
    short* kb    = wfrag + 196608;                     // 1048576 each
    short* qb    = kb + 1048576;
    short* vtb   = qb + 1048576;
    short* pp    = vtb + 1048576;                      // 12582912
    short* po    = pp + (size_t)12582912;              // 8519680

    prep_frag<<<dim3(32, 3), dim3(256), 0, stream>>>(wk, wq, wv, wfrag);
    proj_part<<<dim3(256, 4), dim3(256), 0, stream>>>(x, wfrag, pp);
    proj_combine<<<dim3(256), dim3(256), 0, stream>>>(pp, kb, qb, vtb);
    flash_part<<<dim3(64, 8, 4), dim3(256), 0, stream>>>(qb, kb, vtb, bias, po);
    flash_reduce<<<dim3(1024), dim3(256), 0, stream>>>(po, out);
}